// Round 4
// baseline (387.278 us; speedup 1.0000x reference)
//
#include <hip/hip_runtime.h>

#define A_N 100000
#define B_N 8
#define C_N 80
#define M_N 32
#define IMG4 2000000          // A_N * 20 float4s per image
#define CHUNK4 8192           // float4s per block in streaming kernel
#define BX ((IMG4 + CHUNK4 - 1) / CHUNK4)   // 245 blocks per image

typedef float vfloat4 __attribute__((ext_vector_type(4)));

// Workspace (bytes): [0:32) cls_sum f32[8], [32:64) reg_sum f32[8], [64:96) npos i32[8],
//                    [256: 256+1.6M) meta ushort[B_N*A_N]

// ---------- Kernel 1: anchor assignment + regression loss + meta ----------
__global__ __launch_bounds__(256) void focal_assign(
    const float4* __restrict__ reg4,   // [B, A] float4
    const float4* __restrict__ anc4,   // [A] float4
    const float*  __restrict__ ann,    // [B, 32, 9]
    unsigned short* __restrict__ meta, // [B, A]
    float* __restrict__ reg_sum, int* __restrict__ npos)
{
    __shared__ float annL[M_N][6];   // x0,y0,x1,y1,label,area
    __shared__ float redA[4];
    __shared__ int   redI[4];

    const int b   = blockIdx.y;
    const int a0  = blockIdx.x * 256;
    const int tid = threadIdx.x;

    for (int i = tid; i < M_N * 5; i += 256) {
        int m = i / 5, c = i % 5;
        annL[m][c] = ann[(b * M_N + m) * 9 + c];
    }
    __syncthreads();
    if (tid < M_N) {
        annL[tid][5] = (annL[tid][2] - annL[tid][0]) * (annL[tid][3] - annL[tid][1]);
    }
    __syncthreads();

    const int a = a0 + tid;
    float regacc = 0.0f;
    bool pos = false;

    if (a < A_N) {
        float4 an = anc4[a];
        float aw = an.z - an.x, ah = an.w - an.y;
        float aArea = aw * ah;
        float best = -1.0f; int bidx = 0;
        #pragma unroll 8
        for (int m = 0; m < M_N; ++m) {
            float iw = fminf(an.z, annL[m][2]) - fmaxf(an.x, annL[m][0]);
            float ih = fminf(an.w, annL[m][3]) - fmaxf(an.y, annL[m][1]);
            iw = fmaxf(iw, 0.0f); ih = fmaxf(ih, 0.0f);
            float inter = iw * ih;
            float ua = fmaxf(aArea + annL[m][5] - inter, 1e-8f);
            float iou = inter / ua;
            if (iou > best) { best = iou; bidx = m; }   // strict > == first-max (JAX argmax)
        }
        pos = best >= 0.5f;
        int st = pos ? 2 : (best < 0.4f ? 0 : 1);
        int ci = (int)annL[bidx][4];
        meta[(size_t)b * A_N + a] = (unsigned short)(st | (ci << 2));

        if (pos) {
            float4 r = reg4[(size_t)b * A_N + a];
            float gx0 = annL[bidx][0], gy0 = annL[bidx][1];
            float gx1 = annL[bidx][2], gy1 = annL[bidx][3];
            float gwr = gx1 - gx0, ghr = gy1 - gy0;
            float gcx = gx0 + 0.5f * gwr, gcy = gy0 + 0.5f * ghr;
            float gw = fmaxf(gwr, 1.0f), gh = fmaxf(ghr, 1.0f);
            float acx = an.x + 0.5f * aw, acy = an.y + 0.5f * ah;
            float t0 = (gcx - acx) / aw * 10.0f;
            float t1 = (gcy - acy) / ah * 10.0f;
            float t2 = __logf(gw / aw) * 5.0f;
            float t3 = __logf(gh / ah) * 5.0f;
            float d0 = fabsf(t0 - r.x), d1 = fabsf(t1 - r.y);
            float d2 = fabsf(t2 - r.z), d3 = fabsf(t3 - r.w);
            const float th = 1.0f / 9.0f;
            const float hs = 0.5f / 9.0f;
            regacc  = (d0 <= th) ? 4.5f * d0 * d0 : d0 - hs;
            regacc += (d1 <= th) ? 4.5f * d1 * d1 : d1 - hs;
            regacc += (d2 <= th) ? 4.5f * d2 * d2 : d2 - hs;
            regacc += (d3 <= th) ? 4.5f * d3 * d3 : d3 - hs;
        }
    }

    unsigned long long bal = __ballot(pos);
    #pragma unroll
    for (int o = 32; o > 0; o >>= 1) regacc += __shfl_down(regacc, o, 64);
    int lane = tid & 63, wid = tid >> 6;
    if (lane == 0) { redA[wid] = regacc; redI[wid] = __popcll(bal); }
    __syncthreads();
    if (tid == 0) {
        float rs = redA[0] + redA[1] + redA[2] + redA[3];
        int   np = redI[0] + redI[1] + redI[2] + redI[3];
        if (rs != 0.0f) atomicAdd(&reg_sum[b], rs);
        if (np)         atomicAdd(&npos[b], np);
    }
}

// ---------- Kernel 2: pure streaming focal reduction over classifications ----------
__device__ __forceinline__ float focal_term(vfloat4 v, int st2, int ciL, int c0)
{
    float notIgn = (st2 != 1) ? 1.0f : 0.0f;
    bool  isPos  = (st2 == 2);
    float pv[4] = {v.x, v.y, v.z, v.w};
    float term = 0.0f;
    #pragma unroll
    for (int j = 0; j < 4; ++j) {
        float p = fminf(fmaxf(pv[j], 1e-4f), 1.0f - 1e-4f);
        bool one = isPos && (c0 + j == ciL);
        float alphaf = one ? 0.25f : 0.75f;
        float w      = one ? 1.0f - p : p;
        float arg    = one ? p : 1.0f - p;   // single log, branchless
        term += alphaf * w * w * (-__logf(arg));
    }
    return notIgn * term;
}

__global__ __launch_bounds__(256) void focal_cls(
    const vfloat4* __restrict__ cls4,        // [B, A, 20]
    const unsigned short* __restrict__ meta, // [B, A]
    float* __restrict__ cls_sum)
{
    __shared__ float redB[4];
    const int b   = blockIdx.y;
    const int bx  = blockIdx.x;
    const int tid = threadIdx.x;
    const int i0  = bx * CHUNK4;                       // image-local float4 offset
    const vfloat4* __restrict__ cbase = cls4 + (size_t)b * IMG4 + i0;
    const unsigned short* __restrict__ mbase = meta + (size_t)b * A_N;

    float acc0 = 0.0f, acc1 = 0.0f;

    if (i0 + CHUNK4 <= IMG4) {
        // full tile: 32 trips, compile-time count, no bounds checks
        #pragma unroll 4
        for (int k = 0; k < CHUNK4 / 256; ++k) {
            int io = (k << 8) + tid;
            vfloat4 v = __builtin_nontemporal_load(cbase + io);
            int i  = i0 + io;
            int la = i / 20;
            int c0 = (i - la * 20) * 4;
            unsigned short m = mbase[la];
            float t = focal_term(v, m & 3, m >> 2, c0);
            if (k & 1) acc1 += t; else acc0 += t;
        }
    } else {
        const int n = IMG4 - i0;   // tail block: 1152 float4s
        for (int io = tid; io < n; io += 256) {
            vfloat4 v = __builtin_nontemporal_load(cbase + io);
            int i  = i0 + io;
            int la = i / 20;
            int c0 = (i - la * 20) * 4;
            unsigned short m = mbase[la];
            acc0 += focal_term(v, m & 3, m >> 2, c0);
        }
    }

    float clsacc = acc0 + acc1;
    #pragma unroll
    for (int o = 32; o > 0; o >>= 1) clsacc += __shfl_down(clsacc, o, 64);
    int lane = tid & 63, wid = tid >> 6;
    if (lane == 0) redB[wid] = clsacc;
    __syncthreads();
    if (tid == 0) atomicAdd(&cls_sum[b], redB[0] + redB[1] + redB[2] + redB[3]);
}

__global__ void focal_finalize(const float* __restrict__ cls_sum,
                               const float* __restrict__ reg_sum,
                               const int* __restrict__ npos,
                               float* __restrict__ out)
{
    if (threadIdx.x == 0) {
        float c = 0.0f, r = 0.0f;
        for (int b = 0; b < B_N; ++b) {
            float np = (float)npos[b];
            c += cls_sum[b] / fmaxf(np, 1.0f);
            r += (npos[b] > 0) ? reg_sum[b] / (4.0f * np) : 0.0f;
        }
        out[0] = c / (float)B_N;
        out[1] = r / (float)B_N;
    }
}

extern "C" void kernel_launch(void* const* d_in, const int* in_sizes, int n_in,
                              void* d_out, int out_size, void* d_ws, size_t ws_size,
                              hipStream_t stream) {
    const float* cls = (const float*)d_in[0];   // [B, A, C]
    const float* reg = (const float*)d_in[1];   // [B, A, 4]
    const float* anc = (const float*)d_in[2];   // [1, A, 4]
    const float* ann = (const float*)d_in[3];   // [B, M, 9]

    float* ws      = (float*)d_ws;
    float* cls_sum = ws;                               // 8 floats
    float* reg_sum = ws + 8;                           // 8 floats
    int*   npos    = (int*)(ws + 16);                  // 8 ints
    unsigned short* meta = (unsigned short*)((char*)d_ws + 256);  // 800k ushorts

    (void)hipMemsetAsync(d_ws, 0, 24 * sizeof(float), stream);

    dim3 gridA((A_N + 255) / 256, B_N);
    focal_assign<<<gridA, 256, 0, stream>>>(
        (const float4*)reg, (const float4*)anc, ann, meta, reg_sum, npos);

    dim3 gridC(BX, B_N);
    focal_cls<<<gridC, 256, 0, stream>>>((const vfloat4*)cls, meta, cls_sum);

    focal_finalize<<<1, 64, 0, stream>>>(cls_sum, reg_sum, npos, (float*)d_out);
}